// Round 6
// baseline (4016.871 us; speedup 1.0000x reference)
//
#include <hip/hip_runtime.h>
#include <stdint.h>

#define BN_ 2
#define NPT 16384
#define MPT 8192
#define NROI 128
#define KP 2048

typedef unsigned long long u64;
typedef unsigned u32;

// ---- workspace layout (float offsets) ----
#define FEATS_LEN (4096*352)
#define CNTR_OFF  (FEATS_LEN)
#define CNTC_OFF  (CNTR_OFF + 4096)
#define FRAW_OFF  (CNTC_OFF + 4096)
#define FRAW_LEN  (BN_*NPT*32)
#define GC3_OFF   (FRAW_OFF + FRAW_LEN)
#define GC3_LEN   (BN_*MPT*64)
#define FLAGS_F_OFF (GC3_OFF + GC3_LEN)
#define CX_OFF    (FLAGS_F_OFF + (BN_*NPT)/4)
#define CY_OFF    (CX_OFF + BN_*NPT)
#define CZ_OFF    (CY_OFF + BN_*NPT)
#define SOID_OFF  (CZ_OFF + BN_*NPT)
#define VV_OFF    (SOID_OFF + BN_*NPT)
#define OUT_KP_OFF (4096*128)

// ---------------- helpers ----------------
template <int CTRL>
__device__ __forceinline__ u32 dppmov(u32 v) {
    return (u32)__builtin_amdgcn_update_dpp((int)v, (int)v, CTRL, 0xF, 0xF, false);
}
__device__ __forceinline__ u32 wave_umax_dpp(u32 v) {
#define STG(C) { u32 o = dppmov<C>(v); v = (o > v) ? o : v; }
    STG(0x111) STG(0x112) STG(0x114) STG(0x118) STG(0x142) STG(0x143)
#undef STG
    return (u32)__builtin_amdgcn_readlane((int)v, 63);
}
__device__ __forceinline__ float wave_fmin(float v) {
#define STG(C) { float o = __uint_as_float(dppmov<C>(__float_as_uint(v))); v = fminf(v, o); }
    STG(0x111) STG(0x112) STG(0x114) STG(0x118) STG(0x142) STG(0x143)
#undef STG
    return __uint_as_float((u32)__builtin_amdgcn_readlane((int)__float_as_uint(v), 63));
}
__device__ __forceinline__ float wave_fmax(float v) {
#define STG(C) { float o = __uint_as_float(dppmov<C>(__float_as_uint(v))); v = fmaxf(v, o); }
    STG(0x111) STG(0x112) STG(0x114) STG(0x118) STG(0x142) STG(0x143)
#undef STG
    return __uint_as_float((u32)__builtin_amdgcn_readlane((int)__float_as_uint(v), 63));
}
__device__ __forceinline__ float rdlane(float v, int L) {
    return __uint_as_float((u32)__builtin_amdgcn_readlane((int)__float_as_uint(v), L));
}
__device__ __forceinline__ u32 part4(u32 v) {
    v = (v | (v << 2)) & 0x33u; v = (v | (v << 1)) & 0x55u; return v;
}

// ---------------- K1: ROI validity flags (bit-exact vs reference) ----------------
__global__ void k_flags(const float* __restrict__ pts, const float* __restrict__ bbox,
                        unsigned char* __restrict__ flags) {
#pragma clang fp contract(off)
    __shared__ float rx[NROI], ry[NROI], rz[NROI], rt[NROI];
    int b = blockIdx.x >> 6;
    int t = threadIdx.x;
    if (t < NROI) {
        const float* rr = bbox + (size_t)(b * NROI + t) * 7;
        rx[t] = rr[0]; ry[t] = rr[1]; rz[t] = rr[2];
        float hx = rr[3] * 0.5f, hy = rr[4] * 0.5f, hz = rr[5] * 0.5f;
        rt[t] = sqrtf(((hx * hx) + (hy * hy)) + (hz * hz)) + 2.4f;
    }
    __syncthreads();
    int p = (blockIdx.x & 63) * 256 + t;
    const float* pr = pts + (size_t)(b * NPT + p) * 5;
    float x = pr[0], y = pr[1], z = pr[2];
    float mind = 3.4e38f, th = 0.f;
    for (int r = 0; r < NROI; ++r) {
        float dx = x - rx[r], dy = y - ry[r], dz = z - rz[r];
        float ds = sqrtf(((dx * dx) + (dy * dy)) + (dz * dz));
        if (ds < mind) { mind = ds; th = rt[r]; }
    }
    flags[b * NPT + p] = (mind < th) ? 1 : 0;
}

// ---------------- K2a: Morton counting-sort of valid points ----------------
__global__ void __launch_bounds__(512, 1)
k_sort(const float* __restrict__ pts, const unsigned char* __restrict__ flags,
       float* __restrict__ sxg, float* __restrict__ syg, float* __restrict__ szg,
       int* __restrict__ soidg, int* __restrict__ vg) {
    __shared__ int hist[256];
    __shared__ int wsum[8];
    int b = blockIdx.x, t = threadIdx.x, lane = t & 63, w = t >> 6;
    const float* pbase = pts + (size_t)b * NPT * 5;
    const unsigned char* fb = flags + b * NPT;
    float* SX = sxg + (size_t)b * NPT;
    float* SY = syg + (size_t)b * NPT;
    float* SZ = szg + (size_t)b * NPT;
    int*   SO = soidg + (size_t)b * NPT;

    for (int i = t; i < 256; i += 512) hist[i] = 0;
    __syncthreads();

    int chunk = t * 32;
    u32 fl = 0, cells[8];
#pragma unroll
    for (int i = 0; i < 8; ++i) cells[i] = 0;
    int cnt = 0;
    for (int j = 0; j < 32; ++j) {
        if (fb[chunk + j]) {
            const float* pr = pbase + (size_t)(chunk + j) * 5;
            float x = pr[0], y = pr[1];
            int cxi = (int)fmaxf(0.f, fminf(15.f, (x + 75.2f) * (16.0f / 150.4f)));
            int cyi = (int)fmaxf(0.f, fminf(15.f, (y + 75.2f) * (16.0f / 150.4f)));
            u32 cell = part4((u32)cxi) | (part4((u32)cyi) << 1);
            atomicAdd(&hist[cell], 1);
            cells[j >> 2] |= cell << ((j & 3) * 8);
            fl |= 1u << j;
            ++cnt;
        }
    }
    int s = cnt;
#pragma unroll
    for (int m = 1; m < 64; m <<= 1) s += __shfl_xor(s, m, 64);
    if (lane == 0) wsum[w] = s;
    __syncthreads();
    int V = 0;
    for (int i = 0; i < 8; ++i) V += wsum[i];
    if (t == 0) vg[b] = V;
    __syncthreads();

    int v = (t < 256) ? hist[t] : 0;
    int incl = v;
#pragma unroll
    for (int off = 1; off < 64; off <<= 1) {
        int u = __shfl_up(incl, off, 64);
        if (lane >= off) incl += u;
    }
    if (lane == 63) wsum[w] = incl;
    __syncthreads();
    if (t < 256) {
        int off = 0;
        for (int i = 0; i < w; ++i) off += wsum[i];
        hist[t] = off + incl - v;
    }
    __syncthreads();

    for (int j = 0; j < 32; ++j) {
        if ((fl >> j) & 1u) {
            u32 cell = (cells[j >> 2] >> ((j & 3) * 8)) & 0xFFu;
            int pos = atomicAdd(&hist[cell], 1);
            const float* pr = pbase + (size_t)(chunk + j) * 5;
            SX[pos] = pr[0]; SY[pos] = pr[1]; SZ[pos] = pr[2];
            SO[pos] = chunk + j;
        }
    }
}

// ---------------- FPS core: col-pruned, xyz-carrying candidates, LDS kp buffer ----
template <int NS>
__device__ void fps_core(int t, int lane, int w, int V,
                         const float* __restrict__ SX, const float* __restrict__ SY,
                         const float* __restrict__ SZ, const int* __restrict__ SO,
                         float* cands, float* kbuf, float* __restrict__ kout) {
#pragma clang fp contract(off)
    float px[NS], py[NS], pz[NS], d[NS];
    u32 inv[NS];
    const int wbase = w * 64 * NS;
#pragma unroll
    for (int j = 0; j < NS; ++j) {
        int sid = wbase + j * 64 + lane;
        bool in = sid < V;
        px[j] = in ? SX[sid] : 3e38f;
        py[j] = in ? SY[sid] : 3e38f;
        pz[j] = in ? SZ[sid] : 3e38f;
        d[j]  = in ? 1e10f : -3.0e38f;
        inv[j] = in ? ~(u32)SO[sid] : 0u;
    }
    // column AABBs: lane j caches column j's box (column = 64 consecutive sorted pts)
    float cLx = 3e38f, cLy = 3e38f, cLz = 3e38f;
    float cHx = -3e38f, cHy = -3e38f, cHz = -3e38f;
#pragma unroll
    for (int j = 0; j < NS; ++j) {
        bool in = (wbase + j * 64 + lane) < V;
        float mnx = wave_fmin(px[j]);
        float mny = wave_fmin(py[j]);
        float mnz = wave_fmin(pz[j]);
        float mxx = wave_fmax(in ? px[j] : -3e38f);
        float mxy = wave_fmax(in ? py[j] : -3e38f);
        float mxz = wave_fmax(in ? pz[j] : -3e38f);
        if (lane == j) { cLx = mnx; cLy = mny; cLz = mnz; cHx = mxx; cHy = mxy; cHz = mxz; }
    }

    // prime: local argmax (carry xyz), then wave reduce, cache candidate in regs
    float bestD = -3.4e38f; u32 bestI = 0; float bX = 0.f, bY = 0.f, bZ = 0.f;
#pragma unroll
    for (int j = 0; j < NS; ++j) {
        bool g = (d[j] > bestD) || (d[j] == bestD && inv[j] > bestI);
        bestD = g ? d[j] : bestD; bestI = g ? inv[j] : bestI;
        bX = g ? px[j] : bX; bY = g ? py[j] : bY; bZ = g ? pz[j] : bZ;
    }
    float mD = wave_fmax(bestD);
    u32 ii = (bestD == mD) ? bestI : 0u;
    u32 mI = wave_umax_dpp(ii);
    u64 mm = __ballot(bestD == mD && bestI == mI);
    int L = __ffsll(mm) - 1;
    float cD = mD; u32 cI = mI;
    float cX = rdlane(bX, L), cY = rdlane(bY, L), cZ = rdlane(bZ, L);
    if (lane == 0) {
        float* cb = cands + w * 8;   // buffer 0
        cb[0] = cD; cb[1] = __uint_as_float(cI); cb[2] = cX; cb[3] = cY; cb[4] = cZ;
    }

    for (int k = 0; k < KP; ++k) {
        __syncthreads();
        const float* base = cands + (k & 1) * 32;
        // 4 wave candidates, broadcast (uniform-address) reads
        float4 a0 = *(const float4*)(base + 0);  float z0 = base[4];
        float4 a1 = *(const float4*)(base + 8);  float z1 = base[12];
        float4 a2 = *(const float4*)(base + 16); float z2 = base[20];
        float4 a3 = *(const float4*)(base + 24); float z3 = base[28];
        float wd = a0.x; u32 wi = __float_as_uint(a0.y);
        float wx = a0.z, wy = a0.w, wz = z0;
        { u32 i1 = __float_as_uint(a1.y);
          bool g = (a1.x > wd) || (a1.x == wd && i1 > wi);
          wd = g ? a1.x : wd; wi = g ? i1 : wi; wx = g ? a1.z : wx; wy = g ? a1.w : wy; wz = g ? z1 : wz; }
        { u32 i2 = __float_as_uint(a2.y);
          bool g = (a2.x > wd) || (a2.x == wd && i2 > wi);
          wd = g ? a2.x : wd; wi = g ? i2 : wi; wx = g ? a2.z : wx; wy = g ? a2.w : wy; wz = g ? z2 : wz; }
        { u32 i3 = __float_as_uint(a3.y);
          bool g = (a3.x > wd) || (a3.x == wd && i3 > wi);
          wd = g ? a3.x : wd; wi = g ? i3 : wi; wx = g ? a3.z : wx; wy = g ? a3.w : wy; wz = g ? z3 : wz; }
        if (t == 0) { kbuf[k * 3] = wx; kbuf[k * 3 + 1] = wy; kbuf[k * 3 + 2] = wz; }

        // per-column exact prune (lane j evaluates column j's AABB vs wave's max d)
        float ddx = fmaxf(0.f, fmaxf(cLx - wx, wx - cHx));
        float ddy = fmaxf(0.f, fmaxf(cLy - wy, wy - cHy));
        float ddz = fmaxf(0.f, fmaxf(cLz - wz, wz - cHz));
        float ad2 = (ddx * ddx + ddy * ddy) + ddz * ddz;
        u64 mask = __ballot(!(ad2 > cD * 1.00002f + 1e-6f));
        if (mask) {
            bestD = -3.4e38f; bestI = 0; bX = 0.f; bY = 0.f; bZ = 0.f;
#pragma unroll
            for (int j = 0; j < NS; ++j) {
                if (mask & (1ull << j)) {   // wave-uniform: scalar branch
                    float dx = px[j] - wx, dy = py[j] - wy, dz = pz[j] - wz;
                    float nd = ((dx * dx) + (dy * dy)) + dz * dz;
                    d[j] = fminf(d[j], nd);
                }
                bool g = (d[j] > bestD) || (d[j] == bestD && inv[j] > bestI);
                bestD = g ? d[j] : bestD; bestI = g ? inv[j] : bestI;
                bX = g ? px[j] : bX; bY = g ? py[j] : bY; bZ = g ? pz[j] : bZ;
            }
            mD = wave_fmax(bestD);
            ii = (bestD == mD) ? bestI : 0u;
            mI = wave_umax_dpp(ii);
            mm = __ballot(bestD == mD && bestI == mI);
            L = __ffsll(mm) - 1;
            cD = mD; cI = mI;
            cX = rdlane(bX, L); cY = rdlane(bY, L); cZ = rdlane(bZ, L);
        }
        if (lane == 0) {   // write-only publication from register cache
            float* wb = cands + (((k & 1) ^ 1) * 4 + w) * 8;
            wb[0] = cD; wb[1] = __uint_as_float(cI); wb[2] = cX; wb[3] = cY; wb[4] = cZ;
        }
    }
    __syncthreads();
    for (int i = t; i < KP * 3; i += 256) kout[i] = kbuf[i];
}

// ---------------- K2b: exact FPS (256 thr = 4 waves = 1/SIMD) ----------------
__global__ void __launch_bounds__(256, 1)
k_fps(const float* __restrict__ pts,
      const float* __restrict__ sxg, const float* __restrict__ syg,
      const float* __restrict__ szg, const int* __restrict__ soidg,
      const int* __restrict__ vg, float* __restrict__ kpOut) {
#pragma clang fp contract(off)
    __shared__ __align__(16) float cands[2 * 4 * 8];
    __shared__ float kbuf[KP * 3];
    int b = blockIdx.x, t = threadIdx.x, lane = t & 63, w = t >> 6;
    int V = vg[b];
    const float* SX = sxg + (size_t)b * NPT;
    const float* SY = syg + (size_t)b * NPT;
    const float* SZ = szg + (size_t)b * NPT;
    const int*   SO = soidg + (size_t)b * NPT;
    float* kout = kpOut + (size_t)b * KP * 3;
    if (V == 0) {
        const float* pb = pts + (size_t)b * NPT * 5;
        if (t == 0)
            for (int k = 0; k < KP; ++k) {
                kout[k * 3] = pb[0]; kout[k * 3 + 1] = pb[1]; kout[k * 3 + 2] = pb[2];
            }
        return;
    }
    int nsw = (V + 255) >> 8;
    if (nsw <= 12)      fps_core<12>(t, lane, w, V, SX, SY, SZ, SO, cands, kbuf, kout);
    else if (nsw <= 16) fps_core<16>(t, lane, w, V, SX, SY, SZ, SO, cands, kbuf, kout);
    else if (nsw <= 20) fps_core<20>(t, lane, w, V, SX, SY, SZ, SO, cands, kbuf, kout);
    else if (nsw <= 24) fps_core<24>(t, lane, w, V, SX, SY, SZ, SO, cands, kbuf, kout);
    else if (nsw <= 32) fps_core<32>(t, lane, w, V, SX, SY, SZ, SO, cands, kbuf, kout);
    else if (nsw <= 48) fps_core<48>(t, lane, w, V, SX, SY, SZ, SO, cands, kbuf, kout);
    else                fps_core<64>(t, lane, w, V, SX, SY, SZ, SO, cands, kbuf, kout);
}

// ---------------- K3: bilinear BEV sampling ----------------
__global__ void k_bilinear(const float* __restrict__ sf, const float* __restrict__ kp,
                           float* __restrict__ feats) {
    int bid = blockIdx.x;
    int b = bid >> 11, kk = bid & 2047;
    int c = threadIdx.x;
    const float* kpr = kp + (size_t)(b * KP + kk) * 3;
    float x = kpr[0], y = kpr[1];
    float xi = ((x - (-75.2f)) / 0.1f) / 8.0f;
    float yi = ((y - (-75.2f)) / 0.1f) / 8.0f;
    int x0 = (int)floorf(xi); x0 = min(max(x0, 0), 187);
    int x1 = min(max(x0 + 1, 0), 187);
    int y0 = (int)floorf(yi); y0 = min(max(y0, 0), 187);
    int y1 = min(max(y0 + 1, 0), 187);
    float xf0 = (float)x0, xf1 = (float)x1, yf0 = (float)y0, yf1 = (float)y1;
    float wa = (xf1 - xi) * (yf1 - yi), wb = (xf1 - xi) * (yi - yf0);
    float wc = (xi - xf0) * (yf1 - yi), wd = (xi - xf0) * (yi - yf0);
    const float* plane = sf + (size_t)(b * 256 + c) * 188 * 188;
    float Ia = plane[y0 * 188 + x0], Ib = plane[y1 * 188 + x0];
    float Ic = plane[y0 * 188 + x1], Id = plane[y1 * 188 + x1];
    feats[(size_t)(b * KP + kk) * 352 + c] = Ia * wa + Ib * wb + Ic * wc + Id * wd;
}

// ---------------- K4a: raw point feature MLP ----------------
__global__ void k_fraw(const float* __restrict__ pts, const float* __restrict__ Wr,
                       const float* __restrict__ br, float* __restrict__ fraw) {
    int idx = blockIdx.x * 256 + threadIdx.x;
    int c = idx & 31, n = idx >> 5;
    const float* pr = pts + (size_t)n * 5;
    float v = pr[3] * Wr[c] + pr[4] * Wr[32 + c] + br[c];
    fraw[(size_t)n * 32 + c] = fmaxf(v, 0.f);
}

// ---------------- K4b: conv3 point feature MLP ----------------
__global__ void k_gc3(const float* __restrict__ conv3, const float* __restrict__ Wc,
                      const float* __restrict__ bc, float* __restrict__ gc3) {
    __shared__ float w[4096];
    __shared__ float rf[4][64];
    int t = threadIdx.x;
    for (int i = t; i < 4096; i += 256) w[i] = Wc[i];
    int r = blockIdx.x * 4 + (t >> 6);
    int c = t & 63;
    rf[t >> 6][c] = conv3[(size_t)r * 67 + 3 + c];
    __syncthreads();
    float s = bc[c];
#pragma unroll 8
    for (int k = 0; k < 64; ++k) s = fmaf(rf[t >> 6][k], w[k * 64 + c], s);
    gc3[(size_t)r * 64 + c] = fmaxf(s, 0.f);
}

// ---------------- K5: raw radius aggregation ----------------
__global__ void k_rawagg(const float* __restrict__ pts, const float* __restrict__ kp,
                         const float* __restrict__ fraw, float* __restrict__ feats,
                         float* __restrict__ cntR) {
    __shared__ float sp[2560];
    int bid = blockIdx.x;
    int b = bid >> 7, kb = (bid >> 4) & 7, s = bid & 15;
    int t = threadIdx.x;
    int kk = kb * 256 + t, row = b * KP + kk;
    float kx = kp[row * 3], ky = kp[row * 3 + 1], kz = kp[row * 3 + 2];
    float acc[32];
#pragma unroll
    for (int c = 0; c < 32; ++c) acc[c] = 0.f;
    float cnt = 0.f;
    const float R2 = 0.8f * 0.8f;
    for (int tile = 0; tile < 2; ++tile) {
        int nbase = s * 1024 + tile * 512;
        const float* src = pts + (size_t)(b * NPT + nbase) * 5;
        for (int i = t; i < 2560; i += 256) sp[i] = src[i];
        __syncthreads();
        for (int j = 0; j < 512; ++j) {
            float dx = kx - sp[j * 5], dy = ky - sp[j * 5 + 1], dz = kz - sp[j * 5 + 2];
            float d2 = fmaf(dx, dx, fmaf(dy, dy, dz * dz));
            if (d2 < R2) {
                cnt += 1.f;
                const float* fp = fraw + (size_t)(b * NPT + nbase + j) * 32;
#pragma unroll
                for (int c = 0; c < 32; ++c) acc[c] += fp[c];
            }
        }
        __syncthreads();
    }
    float* dst = feats + (size_t)row * 352 + 256;
#pragma unroll
    for (int c = 0; c < 32; ++c) if (acc[c] != 0.f) atomicAdd(dst + c, acc[c]);
    if (cnt != 0.f) atomicAdd(cntR + row, cnt);
}

// ---------------- K6: conv3 radius aggregation ----------------
__global__ void k_c3agg(const float* __restrict__ conv3, const float* __restrict__ kp,
                        const float* __restrict__ gc3, float* __restrict__ feats,
                        float* __restrict__ cntC) {
    __shared__ float sq[256 * 3];
    int bid = blockIdx.x;
    int b = bid >> 7, kb = (bid >> 4) & 7, s = bid & 15;
    int t = threadIdx.x;
    int kk = kb * 256 + t, row = b * KP + kk;
    float kx = kp[row * 3], ky = kp[row * 3 + 1], kz = kp[row * 3 + 2];
    float acc[64];
#pragma unroll
    for (int c = 0; c < 64; ++c) acc[c] = 0.f;
    float cnt = 0.f;
    const float R2 = 1.6f * 1.6f;
    for (int tile = 0; tile < 2; ++tile) {
        int nbase = s * 512 + tile * 256;
        const float* src = conv3 + (size_t)(b * MPT + nbase + t) * 67;
        sq[t * 3] = src[0]; sq[t * 3 + 1] = src[1]; sq[t * 3 + 2] = src[2];
        __syncthreads();
        for (int j = 0; j < 256; ++j) {
            float dx = kx - sq[j * 3], dy = ky - sq[j * 3 + 1], dz = kz - sq[j * 3 + 2];
            float d2 = fmaf(dx, dx, fmaf(dy, dy, dz * dz));
            if (d2 < R2) {
                cnt += 1.f;
                const float* gp = gc3 + (size_t)(b * MPT + nbase + j) * 64;
#pragma unroll
                for (int c = 0; c < 64; ++c) acc[c] += gp[c];
            }
        }
        __syncthreads();
    }
    float* dst = feats + (size_t)row * 352 + 288;
#pragma unroll
    for (int c = 0; c < 64; ++c) if (acc[c] != 0.f) atomicAdd(dst + c, acc[c]);
    if (cnt != 0.f) atomicAdd(cntC + row, cnt);
}

// ---------------- K7: fuse GEMM + BN + ReLU ----------------
__global__ void k_fuse(const float* __restrict__ feats, const float* __restrict__ cntR,
                       const float* __restrict__ cntC, const float* __restrict__ Wf,
                       const float* __restrict__ gma, const float* __restrict__ bta,
                       const float* __restrict__ mean, const float* __restrict__ var,
                       float* __restrict__ out) {
    __shared__ float a[2][352];
    int r0 = blockIdx.x * 2;
    int t = threadIdx.x;
    for (int i = t; i < 704; i += 256) {
        int rr = i >= 352 ? 1 : 0;
        int k = i - rr * 352;
        float v = feats[(size_t)(r0 + rr) * 352 + k];
        if (k >= 256) {
            float cn = (k < 288) ? cntR[r0 + rr] : cntC[r0 + rr];
            v = v / fmaxf(cn, 1.0f);
        }
        a[rr][k] = v;
    }
    __syncthreads();
    int r = t >> 7, c = t & 127;
    float s = 0.f;
#pragma unroll 4
    for (int k = 0; k < 352; ++k) s = fmaf(a[r][k], Wf[k * 128 + c], s);
    s = (s - mean[c]) * (1.0f / sqrtf(var[c] + 1e-5f)) * gma[c] + bta[c];
    out[(size_t)(r0 + r) * 128 + c] = fmaxf(s, 0.f);
}

// ---------------- launch ----------------
extern "C" void kernel_launch(void* const* d_in, const int* in_sizes, int n_in,
                              void* d_out, int out_size, void* d_ws, size_t ws_size,
                              hipStream_t stream) {
    const float* pts   = (const float*)d_in[0];
    const float* bbox  = (const float*)d_in[1];
    const float* sf    = (const float*)d_in[2];
    const float* conv3 = (const float*)d_in[3];
    const float* Wraw  = (const float*)d_in[4];
    const float* braw  = (const float*)d_in[5];
    const float* Wc3   = (const float*)d_in[6];
    const float* bc3   = (const float*)d_in[7];
    const float* Wf    = (const float*)d_in[8];
    const float* gma   = (const float*)d_in[9];
    const float* bta   = (const float*)d_in[10];
    const float* mean  = (const float*)d_in[11];
    const float* var   = (const float*)d_in[12];

    float* wsf   = (float*)d_ws;
    float* feats = wsf;
    float* cntR  = wsf + CNTR_OFF;
    float* cntC  = wsf + CNTC_OFF;
    float* fraw  = wsf + FRAW_OFF;
    float* gc3   = wsf + GC3_OFF;
    unsigned char* flags = (unsigned char*)(wsf + FLAGS_F_OFF);
    float* sxg   = wsf + CX_OFF;
    float* syg   = wsf + CY_OFF;
    float* szg   = wsf + CZ_OFF;
    int*   soidg = (int*)(wsf + SOID_OFF);
    int*   vg    = (int*)(wsf + VV_OFF);

    float* outp  = (float*)d_out;
    float* kpOut = outp + OUT_KP_OFF;

    hipMemsetAsync(d_ws, 0, (size_t)(FEATS_LEN + 8192) * 4, stream);

    k_flags<<<BN_ * 64, 256, 0, stream>>>(pts, bbox, flags);
    k_sort<<<BN_, 512, 0, stream>>>(pts, flags, sxg, syg, szg, soidg, vg);
    k_fps<<<BN_, 256, 0, stream>>>(pts, sxg, syg, szg, soidg, vg, kpOut);
    k_bilinear<<<BN_ * KP, 256, 0, stream>>>(sf, kpOut, feats);
    k_fraw<<<(BN_ * NPT * 32) / 256, 256, 0, stream>>>(pts, Wraw, braw, fraw);
    k_gc3<<<(BN_ * MPT) / 4, 256, 0, stream>>>(conv3, Wc3, bc3, gc3);
    k_rawagg<<<BN_ * 128, 256, 0, stream>>>(pts, kpOut, fraw, feats, cntR);
    k_c3agg<<<BN_ * 128, 256, 0, stream>>>(conv3, kpOut, gc3, feats, cntC);
    k_fuse<<<2048, 256, 0, stream>>>(feats, cntR, cntC, Wf, gma, bta, mean, var, outp);
}

// Round 7
// 2854.178 us; speedup vs baseline: 1.4074x; 1.4074x over previous
//
#include <hip/hip_runtime.h>
#include <stdint.h>

#define BN_ 2
#define NPT 16384
#define MPT 8192
#define NROI 128
#define KP 2048
#define CAP 5184   // LDS mirror capacity (3*CAP*4 = 62208 B)
#define TF 512     // k_fps threads = 8 waves = 2/SIMD

typedef unsigned long long u64;
typedef unsigned u32;

// ---- workspace layout (float offsets) ----
#define FEATS_LEN (4096*352)
#define CNTR_OFF  (FEATS_LEN)
#define CNTC_OFF  (CNTR_OFF + 4096)
#define FRAW_OFF  (CNTC_OFF + 4096)
#define FRAW_LEN  (BN_*NPT*32)
#define GC3_OFF   (FRAW_OFF + FRAW_LEN)
#define GC3_LEN   (BN_*MPT*64)
#define FLAGS_F_OFF (GC3_OFF + GC3_LEN)
#define CX_OFF    (FLAGS_F_OFF + (BN_*NPT)/4)
#define CY_OFF    (CX_OFF + BN_*NPT)
#define CZ_OFF    (CY_OFF + BN_*NPT)
#define SOID_OFF  (CZ_OFF + BN_*NPT)
#define VV_OFF    (SOID_OFF + BN_*NPT)
#define OUT_KP_OFF (4096*128)

// ---------------- helpers ----------------
__device__ __forceinline__ u32 ordf(float f) {
    u32 b = __float_as_uint(f);
    return b ^ ((u32)(((int)b) >> 31) | 0x80000000u);
}
__device__ __forceinline__ float deord(u32 v) {
    u32 b = (v & 0x80000000u) ? (v ^ 0x80000000u) : ~v;
    return __uint_as_float(b);
}
template <int CTRL>
__device__ __forceinline__ u32 dppmov(u32 v) {
    return (u32)__builtin_amdgcn_update_dpp((int)v, (int)v, CTRL, 0xF, 0xF, false);
}
__device__ __forceinline__ u32 wave_umax_dpp(u32 v) {
#define STG(C) { u32 o = dppmov<C>(v); v = (o > v) ? o : v; }
    STG(0x111) STG(0x112) STG(0x114) STG(0x118) STG(0x142) STG(0x143)
#undef STG
    return (u32)__builtin_amdgcn_readlane((int)v, 63);
}
__device__ __forceinline__ float wave_fmin(float v) {
#define STG(C) { float o = __uint_as_float(dppmov<C>(__float_as_uint(v))); v = fminf(v, o); }
    STG(0x111) STG(0x112) STG(0x114) STG(0x118) STG(0x142) STG(0x143)
#undef STG
    return __uint_as_float((u32)__builtin_amdgcn_readlane((int)__float_as_uint(v), 63));
}
__device__ __forceinline__ float wave_fmax(float v) {
#define STG(C) { float o = __uint_as_float(dppmov<C>(__float_as_uint(v))); v = fmaxf(v, o); }
    STG(0x111) STG(0x112) STG(0x114) STG(0x118) STG(0x142) STG(0x143)
#undef STG
    return __uint_as_float((u32)__builtin_amdgcn_readlane((int)__float_as_uint(v), 63));
}
__device__ __forceinline__ u32 part4(u32 v) {
    v = (v | (v << 2)) & 0x33u; v = (v | (v << 1)) & 0x55u; return v;
}

// ---------------- K1: ROI validity flags (bit-exact vs reference) ----------------
__global__ void k_flags(const float* __restrict__ pts, const float* __restrict__ bbox,
                        unsigned char* __restrict__ flags) {
#pragma clang fp contract(off)
    __shared__ float rx[NROI], ry[NROI], rz[NROI], rt[NROI];
    int b = blockIdx.x >> 6;
    int t = threadIdx.x;
    if (t < NROI) {
        const float* rr = bbox + (size_t)(b * NROI + t) * 7;
        rx[t] = rr[0]; ry[t] = rr[1]; rz[t] = rr[2];
        float hx = rr[3] * 0.5f, hy = rr[4] * 0.5f, hz = rr[5] * 0.5f;
        rt[t] = sqrtf(((hx * hx) + (hy * hy)) + (hz * hz)) + 2.4f;
    }
    __syncthreads();
    int p = (blockIdx.x & 63) * 256 + t;
    const float* pr = pts + (size_t)(b * NPT + p) * 5;
    float x = pr[0], y = pr[1], z = pr[2];
    float mind = 3.4e38f, th = 0.f;
    for (int r = 0; r < NROI; ++r) {
        float dx = x - rx[r], dy = y - ry[r], dz = z - rz[r];
        float ds = sqrtf(((dx * dx) + (dy * dy)) + (dz * dz));
        if (ds < mind) { mind = ds; th = rt[r]; }
    }
    flags[b * NPT + p] = (mind < th) ? 1 : 0;
}

// ---------------- K2a: Morton counting-sort of valid points ----------------
__global__ void __launch_bounds__(512, 1)
k_sort(const float* __restrict__ pts, const unsigned char* __restrict__ flags,
       float* __restrict__ sxg, float* __restrict__ syg, float* __restrict__ szg,
       int* __restrict__ soidg, int* __restrict__ vg) {
    __shared__ int hist[256];
    __shared__ int wsum[8];
    int b = blockIdx.x, t = threadIdx.x, lane = t & 63, w = t >> 6;
    const float* pbase = pts + (size_t)b * NPT * 5;
    const unsigned char* fb = flags + b * NPT;
    float* SX = sxg + (size_t)b * NPT;
    float* SY = syg + (size_t)b * NPT;
    float* SZ = szg + (size_t)b * NPT;
    int*   SO = soidg + (size_t)b * NPT;

    for (int i = t; i < 256; i += 512) hist[i] = 0;
    __syncthreads();

    int chunk = t * 32;
    u32 fl = 0, cells[8];
#pragma unroll
    for (int i = 0; i < 8; ++i) cells[i] = 0;
    int cnt = 0;
    for (int j = 0; j < 32; ++j) {
        if (fb[chunk + j]) {
            const float* pr = pbase + (size_t)(chunk + j) * 5;
            float x = pr[0], y = pr[1];
            int cxi = (int)fmaxf(0.f, fminf(15.f, (x + 75.2f) * (16.0f / 150.4f)));
            int cyi = (int)fmaxf(0.f, fminf(15.f, (y + 75.2f) * (16.0f / 150.4f)));
            u32 cell = part4((u32)cxi) | (part4((u32)cyi) << 1);
            atomicAdd(&hist[cell], 1);
            cells[j >> 2] |= cell << ((j & 3) * 8);
            fl |= 1u << j;
            ++cnt;
        }
    }
    int s = cnt;
#pragma unroll
    for (int m = 1; m < 64; m <<= 1) s += __shfl_xor(s, m, 64);
    if (lane == 0) wsum[w] = s;
    __syncthreads();
    int V = 0;
    for (int i = 0; i < 8; ++i) V += wsum[i];
    if (t == 0) vg[b] = V;
    __syncthreads();

    int v = (t < 256) ? hist[t] : 0;
    int incl = v;
#pragma unroll
    for (int off = 1; off < 64; off <<= 1) {
        int u = __shfl_up(incl, off, 64);
        if (lane >= off) incl += u;
    }
    if (lane == 63) wsum[w] = incl;
    __syncthreads();
    if (t < 256) {
        int off = 0;
        for (int i = 0; i < w; ++i) off += wsum[i];
        hist[t] = off + incl - v;
    }
    __syncthreads();

    for (int j = 0; j < 32; ++j) {
        if ((fl >> j) & 1u) {
            u32 cell = (cells[j >> 2] >> ((j & 3) * 8)) & 0xFFu;
            int pos = atomicAdd(&hist[cell], 1);
            const float* pr = pbase + (size_t)(chunk + j) * 5;
            SX[pos] = pr[0]; SY[pos] = pr[1]; SZ[pos] = pr[2];
            SO[pos] = chunk + j;
        }
    }
}

// ---------------- FPS core: 8 waves, min critical path, column pruning ----------------
template <int NS>
__device__ void fps_core(int t, int lane, int w, int V,
                         const float* __restrict__ SX, const float* __restrict__ SY,
                         const float* __restrict__ SZ, const int* __restrict__ SO,
                         const float* sxm, const float* sym, const float* szm,
                         uint4 (*rkey)[8], float* __restrict__ kout) {
#pragma clang fp contract(off)
    float px[NS], py[NS], pz[NS], d[NS];
    u32 inv[NS];
    const int wbase = w * 64 * NS;
    const int wblane = wbase + lane;
#pragma unroll
    for (int j = 0; j < NS; ++j) {
        int sid = wblane + (j << 6);
        bool in = sid < V;
        px[j] = in ? SX[sid] : 3e38f;
        py[j] = in ? SY[sid] : 3e38f;
        pz[j] = in ? SZ[sid] : 3e38f;
        d[j]  = in ? 1e10f : -3.0e38f;
        inv[j] = in ? ~(u32)SO[sid] : 0u;
    }
    // column AABBs: lane j caches column j's box (column = 64 consecutive sorted pts)
    float cLx = 3e38f, cLy = 3e38f, cLz = 3e38f;
    float cHx = -3e38f, cHy = -3e38f, cHz = -3e38f;
#pragma unroll
    for (int j = 0; j < NS; ++j) {
        bool in = (wblane + (j << 6)) < V;
        float mnx = wave_fmin(px[j]);
        float mny = wave_fmin(py[j]);
        float mnz = wave_fmin(pz[j]);
        float mxx = wave_fmax(in ? px[j] : -3e38f);
        float mxy = wave_fmax(in ? py[j] : -3e38f);
        float mxz = wave_fmax(in ? pz[j] : -3e38f);
        if (lane == j) { cLx = mnx; cLy = mny; cLz = mnz; cHx = mxx; cHy = mxy; cHz = mxz; }
    }

    // prime: per-lane argmax (d, inv), cheap carries
    float bD = -3.4e38f; u32 bI = 0; int bJ = 0;
#pragma unroll
    for (int j = 0; j < NS; ++j) {
        bool g = (d[j] > bD) || (d[j] == bD && inv[j] > bI);
        bD = g ? d[j] : bD; bI = g ? inv[j] : bI; bJ = g ? j : bJ;
    }
    u32 o = ordf(bD);
    u32 cOrd = wave_umax_dpp(o);
    u32 cnd = (o == cOrd) ? bI : 0u;
    u32 cInv = wave_umax_dpp(cnd);
    u64 mm = __ballot(o == cOrd && bI == cInv);
    int L = __ffsll(mm) - 1;
    u32 bS = (u32)(wblane + (bJ << 6));
    u32 cSid = (u32)__builtin_amdgcn_readlane((int)bS, L);
    float bd = deord(cOrd);
    if (lane == 0) rkey[0][w] = make_uint4(cInv, cOrd, cSid, 0u);
    __syncthreads();

    for (int k = 0; k < KP; ++k) {
        int p = k & 1;
        // block select: lane-indexed read (8 cands replicated 8x), full-wave DPP reduce
        uint4 c = rkey[p][lane & 7];
        u32 sO = wave_umax_dpp(c.y);
        u32 sc = (c.y == sO) ? c.x : 0u;
        u32 sI = wave_umax_dpp(sc);
        u64 smm = __ballot(c.y == sO && c.x == sI);
        int sL = __ffsll(smm) - 1;
        u32 wSid = (u32)__builtin_amdgcn_readlane((int)c.z, sL);
        float bx, by, bz;
        if ((int)wSid < CAP) { bx = sxm[wSid]; by = sym[wSid]; bz = szm[wSid]; }
        else                 { bx = SX[wSid];  by = SY[wSid];  bz = SZ[wSid];  }
        if (t == 0) { kout[k * 3] = bx; kout[k * 3 + 1] = by; kout[k * 3 + 2] = bz; }

        // per-column exact prune (conservative margin; R5/R6-proven)
        float ddx = fmaxf(0.f, fmaxf(cLx - bx, bx - cHx));
        float ddy = fmaxf(0.f, fmaxf(cLy - by, by - cHy));
        float ddz = fmaxf(0.f, fmaxf(cLz - bz, bz - cHz));
        float ad2 = (ddx * ddx + ddy * ddy) + ddz * ddz;
        u64 mask = __ballot(!(ad2 > bd * 1.00002f + 1e-6f));
        if (mask) {
            bD = -3.4e38f; bI = 0; bJ = 0;
#pragma unroll
            for (int j = 0; j < NS; ++j) {
                if (mask & (1ull << j)) {   // wave-uniform scalar gate
                    float dx = px[j] - bx, dy = py[j] - by, dz = pz[j] - bz;
                    float nd = ((dx * dx) + (dy * dy)) + (dz * dz);
                    d[j] = fminf(d[j], nd);
                }
                bool g = (d[j] > bD) || (d[j] == bD && inv[j] > bI);
                bD = g ? d[j] : bD; bI = g ? inv[j] : bI; bJ = g ? j : bJ;
            }
            o = ordf(bD);
            cOrd = wave_umax_dpp(o);
            cnd = (o == cOrd) ? bI : 0u;
            cInv = wave_umax_dpp(cnd);
            mm = __ballot(o == cOrd && bI == cInv);
            L = __ffsll(mm) - 1;
            bS = (u32)(wblane + (bJ << 6));
            cSid = (u32)__builtin_amdgcn_readlane((int)bS, L);
            bd = deord(cOrd);
        }
        if (lane == 0) rkey[p ^ 1][w] = make_uint4(cInv, cOrd, cSid, 0u);
        __syncthreads();
    }
}

// ---------------- K2b: exact FPS (512 thr = 8 waves = 2/SIMD) ----------------
__global__ void __launch_bounds__(TF, 2)
k_fps(const float* __restrict__ pts,
      const float* __restrict__ sxg, const float* __restrict__ syg,
      const float* __restrict__ szg, const int* __restrict__ soidg,
      const int* __restrict__ vg, float* __restrict__ kpOut) {
#pragma clang fp contract(off)
    __shared__ float sxm[CAP], sym[CAP], szm[CAP];
    __shared__ __align__(16) uint4 rkey[2][8];
    int b = blockIdx.x, t = threadIdx.x, lane = t & 63, w = t >> 6;
    int V = vg[b];
    const float* SX = sxg + (size_t)b * NPT;
    const float* SY = syg + (size_t)b * NPT;
    const float* SZ = szg + (size_t)b * NPT;
    const int*   SO = soidg + (size_t)b * NPT;
    float* kout = kpOut + (size_t)b * KP * 3;
    if (V == 0) {
        const float* pb = pts + (size_t)b * NPT * 5;
        if (t == 0)
            for (int k = 0; k < KP; ++k) {
                kout[k * 3] = pb[0]; kout[k * 3 + 1] = pb[1]; kout[k * 3 + 2] = pb[2];
            }
        return;
    }
    int lim = V < CAP ? V : CAP;
    for (int i = t; i < lim; i += TF) { sxm[i] = SX[i]; sym[i] = SY[i]; szm[i] = SZ[i]; }
    // (prime phase ends with __syncthreads before first mirror use)
    int nsw = (V + TF - 1) / TF;
    if (nsw <= 6)       fps_core<6 >(t, lane, w, V, SX, SY, SZ, SO, sxm, sym, szm, rkey, kout);
    else if (nsw <= 9)  fps_core<9 >(t, lane, w, V, SX, SY, SZ, SO, sxm, sym, szm, rkey, kout);
    else if (nsw <= 12) fps_core<12>(t, lane, w, V, SX, SY, SZ, SO, sxm, sym, szm, rkey, kout);
    else if (nsw <= 16) fps_core<16>(t, lane, w, V, SX, SY, SZ, SO, sxm, sym, szm, rkey, kout);
    else if (nsw <= 24) fps_core<24>(t, lane, w, V, SX, SY, SZ, SO, sxm, sym, szm, rkey, kout);
    else                fps_core<32>(t, lane, w, V, SX, SY, SZ, SO, sxm, sym, szm, rkey, kout);
}

// ---------------- K3: bilinear BEV sampling ----------------
__global__ void k_bilinear(const float* __restrict__ sf, const float* __restrict__ kp,
                           float* __restrict__ feats) {
    int bid = blockIdx.x;
    int b = bid >> 11, kk = bid & 2047;
    int c = threadIdx.x;
    const float* kpr = kp + (size_t)(b * KP + kk) * 3;
    float x = kpr[0], y = kpr[1];
    float xi = ((x - (-75.2f)) / 0.1f) / 8.0f;
    float yi = ((y - (-75.2f)) / 0.1f) / 8.0f;
    int x0 = (int)floorf(xi); x0 = min(max(x0, 0), 187);
    int x1 = min(max(x0 + 1, 0), 187);
    int y0 = (int)floorf(yi); y0 = min(max(y0, 0), 187);
    int y1 = min(max(y0 + 1, 0), 187);
    float xf0 = (float)x0, xf1 = (float)x1, yf0 = (float)y0, yf1 = (float)y1;
    float wa = (xf1 - xi) * (yf1 - yi), wb = (xf1 - xi) * (yi - yf0);
    float wc = (xi - xf0) * (yf1 - yi), wd = (xi - xf0) * (yi - yf0);
    const float* plane = sf + (size_t)(b * 256 + c) * 188 * 188;
    float Ia = plane[y0 * 188 + x0], Ib = plane[y1 * 188 + x0];
    float Ic = plane[y0 * 188 + x1], Id = plane[y1 * 188 + x1];
    feats[(size_t)(b * KP + kk) * 352 + c] = Ia * wa + Ib * wb + Ic * wc + Id * wd;
}

// ---------------- K4a: raw point feature MLP ----------------
__global__ void k_fraw(const float* __restrict__ pts, const float* __restrict__ Wr,
                       const float* __restrict__ br, float* __restrict__ fraw) {
    int idx = blockIdx.x * 256 + threadIdx.x;
    int c = idx & 31, n = idx >> 5;
    const float* pr = pts + (size_t)n * 5;
    float v = pr[3] * Wr[c] + pr[4] * Wr[32 + c] + br[c];
    fraw[(size_t)n * 32 + c] = fmaxf(v, 0.f);
}

// ---------------- K4b: conv3 point feature MLP ----------------
__global__ void k_gc3(const float* __restrict__ conv3, const float* __restrict__ Wc,
                      const float* __restrict__ bc, float* __restrict__ gc3) {
    __shared__ float w[4096];
    __shared__ float rf[4][64];
    int t = threadIdx.x;
    for (int i = t; i < 4096; i += 256) w[i] = Wc[i];
    int r = blockIdx.x * 4 + (t >> 6);
    int c = t & 63;
    rf[t >> 6][c] = conv3[(size_t)r * 67 + 3 + c];
    __syncthreads();
    float s = bc[c];
#pragma unroll 8
    for (int k = 0; k < 64; ++k) s = fmaf(rf[t >> 6][k], w[k * 64 + c], s);
    gc3[(size_t)r * 64 + c] = fmaxf(s, 0.f);
}

// ---------------- K5: raw radius aggregation ----------------
__global__ void k_rawagg(const float* __restrict__ pts, const float* __restrict__ kp,
                         const float* __restrict__ fraw, float* __restrict__ feats,
                         float* __restrict__ cntR) {
    __shared__ float sp[2560];
    int bid = blockIdx.x;
    int b = bid >> 7, kb = (bid >> 4) & 7, s = bid & 15;
    int t = threadIdx.x;
    int kk = kb * 256 + t, row = b * KP + kk;
    float kx = kp[row * 3], ky = kp[row * 3 + 1], kz = kp[row * 3 + 2];
    float acc[32];
#pragma unroll
    for (int c = 0; c < 32; ++c) acc[c] = 0.f;
    float cnt = 0.f;
    const float R2 = 0.8f * 0.8f;
    for (int tile = 0; tile < 2; ++tile) {
        int nbase = s * 1024 + tile * 512;
        const float* src = pts + (size_t)(b * NPT + nbase) * 5;
        for (int i = t; i < 2560; i += 256) sp[i] = src[i];
        __syncthreads();
        for (int j = 0; j < 512; ++j) {
            float dx = kx - sp[j * 5], dy = ky - sp[j * 5 + 1], dz = kz - sp[j * 5 + 2];
            float d2 = fmaf(dx, dx, fmaf(dy, dy, dz * dz));
            if (d2 < R2) {
                cnt += 1.f;
                const float* fp = fraw + (size_t)(b * NPT + nbase + j) * 32;
#pragma unroll
                for (int c = 0; c < 32; ++c) acc[c] += fp[c];
            }
        }
        __syncthreads();
    }
    float* dst = feats + (size_t)row * 352 + 256;
#pragma unroll
    for (int c = 0; c < 32; ++c) if (acc[c] != 0.f) atomicAdd(dst + c, acc[c]);
    if (cnt != 0.f) atomicAdd(cntR + row, cnt);
}

// ---------------- K6: conv3 radius aggregation ----------------
__global__ void k_c3agg(const float* __restrict__ conv3, const float* __restrict__ kp,
                        const float* __restrict__ gc3, float* __restrict__ feats,
                        float* __restrict__ cntC) {
    __shared__ float sq[256 * 3];
    int bid = blockIdx.x;
    int b = bid >> 7, kb = (bid >> 4) & 7, s = bid & 15;
    int t = threadIdx.x;
    int kk = kb * 256 + t, row = b * KP + kk;
    float kx = kp[row * 3], ky = kp[row * 3 + 1], kz = kp[row * 3 + 2];
    float acc[64];
#pragma unroll
    for (int c = 0; c < 64; ++c) acc[c] = 0.f;
    float cnt = 0.f;
    const float R2 = 1.6f * 1.6f;
    for (int tile = 0; tile < 2; ++tile) {
        int nbase = s * 512 + tile * 256;
        const float* src = conv3 + (size_t)(b * MPT + nbase + t) * 67;
        sq[t * 3] = src[0]; sq[t * 3 + 1] = src[1]; sq[t * 3 + 2] = src[2];
        __syncthreads();
        for (int j = 0; j < 256; ++j) {
            float dx = kx - sq[j * 3], dy = ky - sq[j * 3 + 1], dz = kz - sq[j * 3 + 2];
            float d2 = fmaf(dx, dx, fmaf(dy, dy, dz * dz));
            if (d2 < R2) {
                cnt += 1.f;
                const float* gp = gc3 + (size_t)(b * MPT + nbase + j) * 64;
#pragma unroll
                for (int c = 0; c < 64; ++c) acc[c] += gp[c];
            }
        }
        __syncthreads();
    }
    float* dst = feats + (size_t)row * 352 + 288;
#pragma unroll
    for (int c = 0; c < 64; ++c) if (acc[c] != 0.f) atomicAdd(dst + c, acc[c]);
    if (cnt != 0.f) atomicAdd(cntC + row, cnt);
}

// ---------------- K7: fuse GEMM + BN + ReLU ----------------
__global__ void k_fuse(const float* __restrict__ feats, const float* __restrict__ cntR,
                       const float* __restrict__ cntC, const float* __restrict__ Wf,
                       const float* __restrict__ gma, const float* __restrict__ bta,
                       const float* __restrict__ mean, const float* __restrict__ var,
                       float* __restrict__ out) {
    __shared__ float a[2][352];
    int r0 = blockIdx.x * 2;
    int t = threadIdx.x;
    for (int i = t; i < 704; i += 256) {
        int rr = i >= 352 ? 1 : 0;
        int k = i - rr * 352;
        float v = feats[(size_t)(r0 + rr) * 352 + k];
        if (k >= 256) {
            float cn = (k < 288) ? cntR[r0 + rr] : cntC[r0 + rr];
            v = v / fmaxf(cn, 1.0f);
        }
        a[rr][k] = v;
    }
    __syncthreads();
    int r = t >> 7, c = t & 127;
    float s = 0.f;
#pragma unroll 4
    for (int k = 0; k < 352; ++k) s = fmaf(a[r][k], Wf[k * 128 + c], s);
    s = (s - mean[c]) * (1.0f / sqrtf(var[c] + 1e-5f)) * gma[c] + bta[c];
    out[(size_t)(r0 + r) * 128 + c] = fmaxf(s, 0.f);
}

// ---------------- launch ----------------
extern "C" void kernel_launch(void* const* d_in, const int* in_sizes, int n_in,
                              void* d_out, int out_size, void* d_ws, size_t ws_size,
                              hipStream_t stream) {
    const float* pts   = (const float*)d_in[0];
    const float* bbox  = (const float*)d_in[1];
    const float* sf    = (const float*)d_in[2];
    const float* conv3 = (const float*)d_in[3];
    const float* Wraw  = (const float*)d_in[4];
    const float* braw  = (const float*)d_in[5];
    const float* Wc3   = (const float*)d_in[6];
    const float* bc3   = (const float*)d_in[7];
    const float* Wf    = (const float*)d_in[8];
    const float* gma   = (const float*)d_in[9];
    const float* bta   = (const float*)d_in[10];
    const float* mean  = (const float*)d_in[11];
    const float* var   = (const float*)d_in[12];

    float* wsf   = (float*)d_ws;
    float* feats = wsf;
    float* cntR  = wsf + CNTR_OFF;
    float* cntC  = wsf + CNTC_OFF;
    float* fraw  = wsf + FRAW_OFF;
    float* gc3   = wsf + GC3_OFF;
    unsigned char* flags = (unsigned char*)(wsf + FLAGS_F_OFF);
    float* sxg   = wsf + CX_OFF;
    float* syg   = wsf + CY_OFF;
    float* szg   = wsf + CZ_OFF;
    int*   soidg = (int*)(wsf + SOID_OFF);
    int*   vg    = (int*)(wsf + VV_OFF);

    float* outp  = (float*)d_out;
    float* kpOut = outp + OUT_KP_OFF;

    hipMemsetAsync(d_ws, 0, (size_t)(FEATS_LEN + 8192) * 4, stream);

    k_flags<<<BN_ * 64, 256, 0, stream>>>(pts, bbox, flags);
    k_sort<<<BN_, 512, 0, stream>>>(pts, flags, sxg, syg, szg, soidg, vg);
    k_fps<<<BN_, TF, 0, stream>>>(pts, sxg, syg, szg, soidg, vg, kpOut);
    k_bilinear<<<BN_ * KP, 256, 0, stream>>>(sf, kpOut, feats);
    k_fraw<<<(BN_ * NPT * 32) / 256, 256, 0, stream>>>(pts, Wraw, braw, fraw);
    k_gc3<<<(BN_ * MPT) / 4, 256, 0, stream>>>(conv3, Wc3, bc3, gc3);
    k_rawagg<<<BN_ * 128, 256, 0, stream>>>(pts, kpOut, fraw, feats, cntR);
    k_c3agg<<<BN_ * 128, 256, 0, stream>>>(conv3, kpOut, gc3, feats, cntC);
    k_fuse<<<2048, 256, 0, stream>>>(feats, cntR, cntC, Wf, gma, bta, mean, var, outp);
}

// Round 8
// 2200.363 us; speedup vs baseline: 1.8255x; 1.2971x over previous
//
#include <hip/hip_runtime.h>
#include <stdint.h>

#define BN_ 2
#define NPT 16384
#define MPT 8192
#define NROI 128
#define KP 2048

typedef unsigned long long u64;
typedef unsigned u32;

// ---- workspace layout (float offsets) ----
#define FEATS_LEN (4096*352)
#define CNTR_OFF  (FEATS_LEN)
#define CNTC_OFF  (CNTR_OFF + 4096)
#define FRAW_OFF  (CNTC_OFF + 4096)
#define FRAW_LEN  (BN_*NPT*32)
#define GC3_OFF   (FRAW_OFF + FRAW_LEN)
#define GC3_LEN   (BN_*MPT*64)
#define FLAGS_F_OFF (GC3_OFF + GC3_LEN)      // flags (bytes) at this float offset
#define CW_OFF    (FLAGS_F_OFF + (BN_*NPT)/4) // float4 compacted coords
#define OUT_KP_OFF (4096*128)                // keypoints region inside d_out

// ---------------- helpers ----------------
__device__ __forceinline__ u32 ordf(float f) {
    u32 b = __float_as_uint(f);
    return b ^ ((u32)(((int)b) >> 31) | 0x80000000u);
}
template <int CTRL>
__device__ __forceinline__ u32 dppmov(u32 v) {
    return (u32)__builtin_amdgcn_update_dpp((int)v, (int)v, CTRL, 0xF, 0xF, false);
}
// Wave64 max via DPP; result broadcast via readlane(63).
__device__ __forceinline__ u32 wave_umax_dpp(u32 v) {
#define STG(C) { u32 o = dppmov<C>(v); v = (o > v) ? o : v; }
    STG(0x111) STG(0x112) STG(0x114) STG(0x118) STG(0x142) STG(0x143)
#undef STG
    return (u32)__builtin_amdgcn_readlane((int)v, 63);
}

// ---------------- K1: ROI validity flags (bit-exact vs reference) ----------------
__global__ void k_flags(const float* __restrict__ pts, const float* __restrict__ bbox,
                        unsigned char* __restrict__ flags) {
#pragma clang fp contract(off)
    __shared__ float rx[NROI], ry[NROI], rz[NROI], rt[NROI];
    int b = blockIdx.x >> 6;
    int t = threadIdx.x;
    if (t < NROI) {
        const float* rr = bbox + (size_t)(b * NROI + t) * 7;
        rx[t] = rr[0]; ry[t] = rr[1]; rz[t] = rr[2];
        float hx = rr[3] * 0.5f, hy = rr[4] * 0.5f, hz = rr[5] * 0.5f;
        rt[t] = sqrtf(((hx * hx) + (hy * hy)) + (hz * hz)) + 2.4f;
    }
    __syncthreads();
    int p = (blockIdx.x & 63) * 256 + t;
    const float* pr = pts + (size_t)(b * NPT + p) * 5;
    float x = pr[0], y = pr[1], z = pr[2];
    float mind = 3.4e38f, th = 0.f;
    for (int r = 0; r < NROI; ++r) {
        float dx = x - rx[r], dy = y - ry[r], dz = z - rz[r];
        float ds = sqrtf(((dx * dx) + (dy * dy)) + (dz * dz));
        if (ds < mind) { mind = ds; th = rt[r]; }   // strict < : first-min == np.argmin
    }
    flags[b * NPT + p] = (mind < th) ? 1 : 0;
}

// ---------------- FPS inner loop, compile-time slot count NS (R3 skeleton) ---------
// Changes vs R3 (1870 us measured): keypoints buffered in LDS (no in-loop global
// stores -> no vmcnt drain at the barrier); winner xyz via one uniform float4
// global load from the L2-hot compacted array (mirror removed to fit kbuf).
template <int NS>
__device__ __forceinline__ void fps_loop(
    int t, int lane, int w, int V,
    const float4* __restrict__ cw,
    uint2 (*rkey)[4],                 // LDS, [2][4]
    float* kbuf,                      // LDS, KP*3
    float* __restrict__ kout) {
#pragma clang fp contract(off)
    float px[NS], py[NS], pz[NS], d[NS];
#pragma unroll
    for (int j = 0; j < NS; ++j) {
        int id = (j << 8) + t;
        bool in = id < V;
        float4 q = in ? cw[id] : make_float4(1e18f, 1e18f, 1e18f, 0.f);
        px[j] = q.x; py[j] = q.y; pz[j] = q.z;
        d[j]  = in ? 1e10f : -3.0e38f;
    }

    // prime: argmax over initial d (ties -> lowest j, then min gid across lanes)
    float bestD = -3.4e38f; int bestJ = 0;
#pragma unroll
    for (int j = 0; j < NS; ++j)
        if (d[j] > bestD) { bestD = d[j]; bestJ = j; }
    unsigned gid = (unsigned)((bestJ << 8) + t);
    unsigned myOrd = ordf(bestD);
    unsigned maxOrd = wave_umax_dpp(myOrd);
    unsigned inv = (myOrd == maxOrd) ? (0xFFFFFFFFu - gid) : 0u;
    unsigned maxInv = wave_umax_dpp(inv);
    if (lane == 0) rkey[0][w] = make_uint2(maxOrd, maxInv);
    __syncthreads();

    for (int k = 0; k < KP; ++k) {
        int p = k & 1;
        // block winner among 4 wave candidates (uniform broadcast reads)
        uint2 c0 = rkey[p][0], c1 = rkey[p][1], c2 = rkey[p][2], c3 = rkey[p][3];
        uint2 m0 = (c1.x > c0.x || (c1.x == c0.x && c1.y > c0.y)) ? c1 : c0;
        uint2 m1 = (c3.x > c2.x || (c3.x == c2.x && c3.y > c2.y)) ? c3 : c2;
        uint2 win = (m1.x > m0.x || (m1.x == m0.x && m1.y > m0.y)) ? m1 : m0;
        unsigned wid = 0xFFFFFFFFu - win.y;
        float4 wq = cw[wid];          // uniform, L1/L2-hot
        float bx = wq.x, by = wq.y, bz = wq.z;
        if (t == 0) { kbuf[k * 3] = bx; kbuf[k * 3 + 1] = by; kbuf[k * 3 + 2] = bz; }

        // update + fused local argmax (exact: no fp contraction)
        bestD = -3.4e38f; bestJ = 0;
#pragma unroll
        for (int j = 0; j < NS; ++j) {
            float dx = px[j] - bx, dy = py[j] - by, dz = pz[j] - bz;
            float nd = ((dx * dx) + (dy * dy)) + (dz * dz);
            float dn = fminf(d[j], nd);
            d[j] = dn;
            if (dn > bestD) { bestD = dn; bestJ = j; }
        }
        gid = (unsigned)((bestJ << 8) + t);
        myOrd = ordf(bestD);
        maxOrd = wave_umax_dpp(myOrd);
        inv = (myOrd == maxOrd) ? (0xFFFFFFFFu - gid) : 0u;
        maxInv = wave_umax_dpp(inv);
        if (lane == 0) rkey[p ^ 1][w] = make_uint2(maxOrd, maxInv);
        __syncthreads();
    }
    // flush keypoints LDS -> global (coalesced, once)
    for (int i = t; i < KP * 3; i += 256) kout[i] = kbuf[i];
}

// ---------------- K2: compaction (via global ws) + exact FPS ----------------
// 256 threads = 4 waves = 1 wave/SIMD (R3 configuration).
__global__ void __launch_bounds__(256, 1)
k_fps(const float* __restrict__ pts, const unsigned char* __restrict__ flags,
      float4* __restrict__ cwg, float* __restrict__ kpOut) {
#pragma clang fp contract(off)
    __shared__ uint2 rkey[2][4];
    __shared__ int wtot[4];
    __shared__ float kbuf[KP * 3];

    int b = blockIdx.x;
    int t = threadIdx.x;
    int lane = t & 63, w = t >> 6;
    int chunk = t * 64;   // 64 contiguous input points per thread
    const float* pbase = pts + (size_t)b * NPT * 5;
    const unsigned char* fbase = flags + b * NPT;
    float4* cw = cwg + (size_t)b * NPT;

    // pass 1: count valid in my chunk
    int cnt = 0;
    for (int j = 0; j < 64; ++j) cnt += fbase[chunk + j] ? 1 : 0;
    int incl = cnt;
#pragma unroll
    for (int off = 1; off < 64; off <<= 1) {
        int v = __shfl_up(incl, off, 64);
        if (lane >= off) incl += v;
    }
    if (lane == 63) wtot[w] = incl;
    __syncthreads();
    int waveBase = 0, V = 0;
    for (int i = 0; i < 4; ++i) { int wv = wtot[i]; V += wv; if (i < w) waveBase += wv; }
    int pos = waveBase + incl - cnt;

    // pass 2: stable scatter of compacted coords (float4) to global ws
    for (int j = 0; j < 64; ++j) {
        if (fbase[chunk + j]) {
            const float* pr = pbase + (size_t)(chunk + j) * 5;
            cw[pos] = make_float4(pr[0], pr[1], pr[2], 0.f);
            ++pos;
        }
    }
    __syncthreads();   // workgroup fence: scatter visible to block (write-through L1)

    float* kout = kpOut + (size_t)b * KP * 3;
    if (V == 0) {      // degenerate: reference picks index 0 every step
        if (t == 0)
            for (int k = 0; k < KP; ++k) {
                kout[k * 3] = pbase[0]; kout[k * 3 + 1] = pbase[1]; kout[k * 3 + 2] = pbase[2];
            }
        return;
    }
    int jm = (V + 255) >> 8;
    if (jm <= 20)      fps_loop<20>(t, lane, w, V, cw, rkey, kbuf, kout);
    else if (jm <= 24) fps_loop<24>(t, lane, w, V, cw, rkey, kbuf, kout);
    else if (jm <= 28) fps_loop<28>(t, lane, w, V, cw, rkey, kbuf, kout);
    else               fps_loop<32>(t, lane, w, V, cw, rkey, kbuf, kout);
}

// ---------------- K3: bilinear BEV sampling ----------------
__global__ void k_bilinear(const float* __restrict__ sf, const float* __restrict__ kp,
                           float* __restrict__ feats) {
    int bid = blockIdx.x;
    int b = bid >> 11, kk = bid & 2047;
    int c = threadIdx.x;
    const float* kpr = kp + (size_t)(b * KP + kk) * 3;
    float x = kpr[0], y = kpr[1];
    float xi = ((x - (-75.2f)) / 0.1f) / 8.0f;
    float yi = ((y - (-75.2f)) / 0.1f) / 8.0f;
    int x0 = (int)floorf(xi); x0 = min(max(x0, 0), 187);
    int x1 = min(max(x0 + 1, 0), 187);
    int y0 = (int)floorf(yi); y0 = min(max(y0, 0), 187);
    int y1 = min(max(y0 + 1, 0), 187);
    float xf0 = (float)x0, xf1 = (float)x1, yf0 = (float)y0, yf1 = (float)y1;
    float wa = (xf1 - xi) * (yf1 - yi), wb = (xf1 - xi) * (yi - yf0);
    float wc = (xi - xf0) * (yf1 - yi), wd = (xi - xf0) * (yi - yf0);
    const float* plane = sf + (size_t)(b * 256 + c) * 188 * 188;
    float Ia = plane[y0 * 188 + x0], Ib = plane[y1 * 188 + x0];
    float Ic = plane[y0 * 188 + x1], Id = plane[y1 * 188 + x1];
    feats[(size_t)(b * KP + kk) * 352 + c] = Ia * wa + Ib * wb + Ic * wc + Id * wd;
}

// ---------------- K4a: raw point feature MLP ----------------
__global__ void k_fraw(const float* __restrict__ pts, const float* __restrict__ Wr,
                       const float* __restrict__ br, float* __restrict__ fraw) {
    int idx = blockIdx.x * 256 + threadIdx.x;   // < BN_*NPT*32
    int c = idx & 31, n = idx >> 5;
    const float* pr = pts + (size_t)n * 5;
    float v = pr[3] * Wr[c] + pr[4] * Wr[32 + c] + br[c];
    fraw[(size_t)n * 32 + c] = fmaxf(v, 0.f);
}

// ---------------- K4b: conv3 point feature MLP ----------------
__global__ void k_gc3(const float* __restrict__ conv3, const float* __restrict__ Wc,
                      const float* __restrict__ bc, float* __restrict__ gc3) {
    __shared__ float w[4096];
    __shared__ float rf[4][64];
    int t = threadIdx.x;
    for (int i = t; i < 4096; i += 256) w[i] = Wc[i];
    int r = blockIdx.x * 4 + (t >> 6);
    int c = t & 63;
    rf[t >> 6][c] = conv3[(size_t)r * 67 + 3 + c];
    __syncthreads();
    float s = bc[c];
#pragma unroll 8
    for (int k = 0; k < 64; ++k) s = fmaf(rf[t >> 6][k], w[k * 64 + c], s);
    gc3[(size_t)r * 64 + c] = fmaxf(s, 0.f);
}

// ---------------- K5: raw radius aggregation ----------------
__global__ void k_rawagg(const float* __restrict__ pts, const float* __restrict__ kp,
                         const float* __restrict__ fraw, float* __restrict__ feats,
                         float* __restrict__ cntR) {
    __shared__ float sp[2560];
    int bid = blockIdx.x;
    int b = bid >> 7, kb = (bid >> 4) & 7, s = bid & 15;
    int t = threadIdx.x;
    int kk = kb * 256 + t, row = b * KP + kk;
    float kx = kp[row * 3], ky = kp[row * 3 + 1], kz = kp[row * 3 + 2];
    float acc[32];
#pragma unroll
    for (int c = 0; c < 32; ++c) acc[c] = 0.f;
    float cnt = 0.f;
    const float R2 = 0.8f * 0.8f;
    for (int tile = 0; tile < 2; ++tile) {
        int nbase = s * 1024 + tile * 512;
        const float* src = pts + (size_t)(b * NPT + nbase) * 5;
        for (int i = t; i < 2560; i += 256) sp[i] = src[i];
        __syncthreads();
        for (int j = 0; j < 512; ++j) {
            float dx = kx - sp[j * 5], dy = ky - sp[j * 5 + 1], dz = kz - sp[j * 5 + 2];
            float d2 = fmaf(dx, dx, fmaf(dy, dy, dz * dz));
            if (d2 < R2) {
                cnt += 1.f;
                const float* fp = fraw + (size_t)(b * NPT + nbase + j) * 32;
#pragma unroll
                for (int c = 0; c < 32; ++c) acc[c] += fp[c];
            }
        }
        __syncthreads();
    }
    float* dst = feats + (size_t)row * 352 + 256;
#pragma unroll
    for (int c = 0; c < 32; ++c) if (acc[c] != 0.f) atomicAdd(dst + c, acc[c]);
    if (cnt != 0.f) atomicAdd(cntR + row, cnt);
}

// ---------------- K6: conv3 radius aggregation ----------------
__global__ void k_c3agg(const float* __restrict__ conv3, const float* __restrict__ kp,
                        const float* __restrict__ gc3, float* __restrict__ feats,
                        float* __restrict__ cntC) {
    __shared__ float sq[256 * 3];
    int bid = blockIdx.x;
    int b = bid >> 7, kb = (bid >> 4) & 7, s = bid & 15;
    int t = threadIdx.x;
    int kk = kb * 256 + t, row = b * KP + kk;
    float kx = kp[row * 3], ky = kp[row * 3 + 1], kz = kp[row * 3 + 2];
    float acc[64];
#pragma unroll
    for (int c = 0; c < 64; ++c) acc[c] = 0.f;
    float cnt = 0.f;
    const float R2 = 1.6f * 1.6f;
    for (int tile = 0; tile < 2; ++tile) {
        int nbase = s * 512 + tile * 256;
        const float* src = conv3 + (size_t)(b * MPT + nbase + t) * 67;
        sq[t * 3] = src[0]; sq[t * 3 + 1] = src[1]; sq[t * 3 + 2] = src[2];
        __syncthreads();
        for (int j = 0; j < 256; ++j) {
            float dx = kx - sq[j * 3], dy = ky - sq[j * 3 + 1], dz = kz - sq[j * 3 + 2];
            float d2 = fmaf(dx, dx, fmaf(dy, dy, dz * dz));
            if (d2 < R2) {
                cnt += 1.f;
                const float* gp = gc3 + (size_t)(b * MPT + nbase + j) * 64;
#pragma unroll
                for (int c = 0; c < 64; ++c) acc[c] += gp[c];
            }
        }
        __syncthreads();
    }
    float* dst = feats + (size_t)row * 352 + 288;
#pragma unroll
    for (int c = 0; c < 64; ++c) if (acc[c] != 0.f) atomicAdd(dst + c, acc[c]);
    if (cnt != 0.f) atomicAdd(cntC + row, cnt);
}

// ---------------- K7: fuse GEMM + BN + ReLU ----------------
__global__ void k_fuse(const float* __restrict__ feats, const float* __restrict__ cntR,
                       const float* __restrict__ cntC, const float* __restrict__ Wf,
                       const float* __restrict__ gma, const float* __restrict__ bta,
                       const float* __restrict__ mean, const float* __restrict__ var,
                       float* __restrict__ out) {
    __shared__ float a[2][352];
    int r0 = blockIdx.x * 2;
    int t = threadIdx.x;
    for (int i = t; i < 704; i += 256) {
        int rr = i >= 352 ? 1 : 0;
        int k = i - rr * 352;
        float v = feats[(size_t)(r0 + rr) * 352 + k];
        if (k >= 256) {
            float cn = (k < 288) ? cntR[r0 + rr] : cntC[r0 + rr];
            v = v / fmaxf(cn, 1.0f);
        }
        a[rr][k] = v;
    }
    __syncthreads();
    int r = t >> 7, c = t & 127;
    float s = 0.f;
#pragma unroll 4
    for (int k = 0; k < 352; ++k) s = fmaf(a[r][k], Wf[k * 128 + c], s);
    s = (s - mean[c]) * (1.0f / sqrtf(var[c] + 1e-5f)) * gma[c] + bta[c];
    out[(size_t)(r0 + r) * 128 + c] = fmaxf(s, 0.f);
}

// ---------------- launch ----------------
extern "C" void kernel_launch(void* const* d_in, const int* in_sizes, int n_in,
                              void* d_out, int out_size, void* d_ws, size_t ws_size,
                              hipStream_t stream) {
    const float* pts   = (const float*)d_in[0];
    const float* bbox  = (const float*)d_in[1];
    const float* sf    = (const float*)d_in[2];
    const float* conv3 = (const float*)d_in[3];
    const float* Wraw  = (const float*)d_in[4];
    const float* braw  = (const float*)d_in[5];
    const float* Wc3   = (const float*)d_in[6];
    const float* bc3   = (const float*)d_in[7];
    const float* Wf    = (const float*)d_in[8];
    const float* gma   = (const float*)d_in[9];
    const float* bta   = (const float*)d_in[10];
    const float* mean  = (const float*)d_in[11];
    const float* var   = (const float*)d_in[12];

    float* wsf   = (float*)d_ws;
    float* feats = wsf;
    float* cntR  = wsf + CNTR_OFF;
    float* cntC  = wsf + CNTC_OFF;
    float* fraw  = wsf + FRAW_OFF;
    float* gc3   = wsf + GC3_OFF;
    unsigned char* flags = (unsigned char*)(wsf + FLAGS_F_OFF);
    float4* cwg  = (float4*)(wsf + CW_OFF);

    float* outp  = (float*)d_out;
    float* kpOut = outp + OUT_KP_OFF;

    // zero feats + counters (atomically accumulated later)
    hipMemsetAsync(d_ws, 0, (size_t)(FEATS_LEN + 8192) * 4, stream);

    k_flags<<<BN_ * 64, 256, 0, stream>>>(pts, bbox, flags);
    k_fps<<<BN_, 256, 0, stream>>>(pts, flags, cwg, kpOut);
    k_bilinear<<<BN_ * KP, 256, 0, stream>>>(sf, kpOut, feats);
    k_fraw<<<(BN_ * NPT * 32) / 256, 256, 0, stream>>>(pts, Wraw, braw, fraw);
    k_gc3<<<(BN_ * MPT) / 4, 256, 0, stream>>>(conv3, Wc3, bc3, gc3);
    k_rawagg<<<BN_ * 128, 256, 0, stream>>>(pts, kpOut, fraw, feats, cntR);
    k_c3agg<<<BN_ * 128, 256, 0, stream>>>(conv3, kpOut, gc3, feats, cntC);
    k_fuse<<<2048, 256, 0, stream>>>(feats, cntR, cntC, Wf, gma, bta, mean, var, outp);
}